// Round 1
// baseline (534.007 us; speedup 1.0000x reference)
//
#include <hip/hip_runtime.h>

#define DIM 256
#define NHEADS 8
#define HDIM 32

// ---------------------------------------------------------------------------
// Tiled SGEMM: C[M,N] = A[M,K] @ B[K,N] (+ bias[N] if bias != nullptr)
// 64x64 tile, BK=16, 256 threads, 4x4 micro-tile per thread.
// ---------------------------------------------------------------------------
__global__ __launch_bounds__(256) void sgemm64(const float* __restrict__ A,
                                               const float* __restrict__ Bm,
                                               const float* __restrict__ bias,
                                               float* __restrict__ C,
                                               int M, int N, int K) {
    constexpr int BM = 64, BN = 64, BK = 16;
    __shared__ float As[BK][BM + 1];   // transposed store, padded
    __shared__ float Bs[BK][BN];
    const int t  = threadIdx.x;
    const int tx = t & 15, ty = t >> 4;
    const int m0 = blockIdx.y * BM, n0 = blockIdx.x * BN;
    float c[4][4] = {};
    for (int k0 = 0; k0 < K; k0 += BK) {
        // A tile: 64 rows x 16 k. 16 consecutive lanes read 16 consecutive k.
        #pragma unroll
        for (int i = 0; i < 4; ++i) {
            int idx = t + i * 256;
            int k = idx & 15, m = idx >> 4;
            As[k][m] = A[(size_t)(m0 + m) * K + (k0 + k)];
        }
        // B tile: 16 k-rows x 64 n. 64 consecutive lanes read one row.
        #pragma unroll
        for (int i = 0; i < 4; ++i) {
            int idx = t + i * 256;
            int nn = idx & 63, k = idx >> 6;
            Bs[k][nn] = Bm[(size_t)(k0 + k) * N + (n0 + nn)];
        }
        __syncthreads();
        #pragma unroll
        for (int kk = 0; kk < BK; ++kk) {
            float a[4], b[4];
            #pragma unroll
            for (int i = 0; i < 4; ++i) a[i] = As[kk][ty * 4 + i];
            #pragma unroll
            for (int j = 0; j < 4; ++j) b[j] = Bs[kk][tx * 4 + j];
            #pragma unroll
            for (int i = 0; i < 4; ++i)
                #pragma unroll
                for (int j = 0; j < 4; ++j)
                    c[i][j] += a[i] * b[j];
        }
        __syncthreads();
    }
    #pragma unroll
    for (int i = 0; i < 4; ++i) {
        int m = m0 + ty * 4 + i;
        float4 v;
        v.x = c[i][0]; v.y = c[i][1]; v.z = c[i][2]; v.w = c[i][3];
        if (bias != nullptr) {
            const float4 bb = *reinterpret_cast<const float4*>(&bias[n0 + tx * 4]);
            v.x += bb.x; v.y += bb.y; v.z += bb.z; v.w += bb.w;
        }
        *reinterpret_cast<float4*>(&C[(size_t)m * N + n0 + tx * 4]) = v;
    }
}

// ---------------------------------------------------------------------------
// Flash-style attention (unnormalized exp, matches KeOps reference exactly):
// one block per (b, h, 64-query tile); iterate 64-key tiles; es tile in LDS;
// per-query running denom; numer accumulated in registers (4q x 2d / thread).
// qkv layout: [b, n, 768] with q|k|v at col offsets 0|256|512, head h at +h*32.
// Output layout [b, n, h*hd] = [8192, 256] row-major, feeds GEMM2 directly.
// ---------------------------------------------------------------------------
__global__ __launch_bounds__(256) void attn64(const float* __restrict__ qkv,
                                              float* __restrict__ outp, int n) {
    constexpr int QT = 64, KT = 64;
    __shared__ float qs[QT][HDIM + 1];
    __shared__ float ks[KT][HDIM + 1];
    __shared__ float vs[KT][HDIM + 1];
    __shared__ float es[QT][KT + 1];
    __shared__ float denom[QT];
    const int nqt = n / QT;
    const int bid = blockIdx.x;
    const int qt = bid % nqt;
    const int h  = (bid / nqt) % NHEADS;
    const int b  = bid / (nqt * NHEADS);
    const int t  = threadIdx.x;
    const int tx = t & 15, ty = t >> 4;
    const float scale = 0.17677669529663687f;  // 32^-0.5
    const float* base = qkv + (size_t)b * n * (3 * DIM);
    const int q0 = qt * QT;

    // Load + scale Q tile: 64x32
    #pragma unroll
    for (int i = 0; i < 8; ++i) {
        int idx = t + i * 256;
        int d = idx & (HDIM - 1), qq = idx >> 5;
        qs[qq][d] = base[(size_t)(q0 + qq) * (3 * DIM) + h * HDIM + d] * scale;
    }
    if (t < QT) denom[t] = 0.f;
    float numer[4][2] = {};
    __syncthreads();

    for (int k0 = 0; k0 < n; k0 += KT) {
        // Load K, V tiles: 64x32 each
        #pragma unroll
        for (int i = 0; i < 8; ++i) {
            int idx = t + i * 256;
            int d = idx & (HDIM - 1), kk = idx >> 5;
            const float* kb = base + (size_t)(k0 + kk) * (3 * DIM) + h * HDIM + d;
            ks[kk][d] = kb[DIM];
            vs[kk][d] = kb[2 * DIM];
        }
        __syncthreads();

        // S = (scaled q) . k  — 4x4 scores per thread, then e = exp(S) to LDS
        float s[4][4] = {};
        #pragma unroll
        for (int d = 0; d < HDIM; ++d) {
            float a[4], bb[4];
            #pragma unroll
            for (int i = 0; i < 4; ++i) a[i] = qs[ty * 4 + i][d];
            #pragma unroll
            for (int j = 0; j < 4; ++j) bb[j] = ks[tx * 4 + j][d];
            #pragma unroll
            for (int i = 0; i < 4; ++i)
                #pragma unroll
                for (int j = 0; j < 4; ++j) s[i][j] += a[i] * bb[j];
        }
        #pragma unroll
        for (int i = 0; i < 4; ++i)
            #pragma unroll
            for (int j = 0; j < 4; ++j)
                es[ty * 4 + i][tx * 4 + j] = __expf(s[i][j]);
        __syncthreads();

        // Running denominator: one thread per query row
        if (t < QT) {
            float sum = 0.f;
            #pragma unroll 8
            for (int j = 0; j < KT; ++j) sum += es[t][j];
            denom[t] += sum;
        }
        // PV: numer[4q][2d] per thread (q rows ty*4.., dims tx*2, tx*2+1)
        #pragma unroll 8
        for (int kk = 0; kk < KT; ++kk) {
            float v0 = vs[kk][tx * 2], v1 = vs[kk][tx * 2 + 1];
            #pragma unroll
            for (int i = 0; i < 4; ++i) {
                float e = es[ty * 4 + i][kk];
                numer[i][0] += e * v0;
                numer[i][1] += e * v1;
            }
        }
        __syncthreads();
    }

    #pragma unroll
    for (int i = 0; i < 4; ++i) {
        int q = q0 + ty * 4 + i;
        float r = 1.0f / (denom[ty * 4 + i] + 1e-6f);
        size_t o = ((size_t)b * n + q) * DIM + h * HDIM + tx * 2;
        outp[o]     = numer[i][0] * r;
        outp[o + 1] = numer[i][1] * r;
    }
}

extern "C" void kernel_launch(void* const* d_in, const int* in_sizes, int n_in,
                              void* d_out, int out_size, void* d_ws, size_t ws_size,
                              hipStream_t stream) {
    const float* x    = (const float*)d_in[0];
    const float* Wqkv = (const float*)d_in[1];
    const float* Wout = (const float*)d_in[2];
    const float* bout = (const float*)d_in[3];
    float* out = (float*)d_out;
    const int B = 4, N = 2048;
    const int M = B * N;                       // 8192
    float* qkv  = (float*)d_ws;                // [8192, 768]
    float* attn = qkv + (size_t)M * 3 * DIM;   // [8192, 256]

    // qkv = x @ Wqkv
    dim3 g1(3 * DIM / 64, M / 64);
    hipLaunchKernelGGL(sgemm64, g1, dim3(256), 0, stream, x, Wqkv, nullptr, qkv,
                       M, 3 * DIM, DIM);
    // attention
    hipLaunchKernelGGL(attn64, dim3(B * NHEADS * (N / 64)), dim3(256), 0, stream,
                       qkv, attn, N);
    // out = attn @ Wout + bout
    dim3 g2(DIM / 64, M / 64);
    hipLaunchKernelGGL(sgemm64, g2, dim3(256), 0, stream, attn, Wout, bout, out,
                       M, DIM, DIM);
}

// Round 2
// 197.548 us; speedup vs baseline: 2.7032x; 2.7032x over previous
//
#include <hip/hip_runtime.h>

#define DIM 256
#define NHEADS 8
#define HDIM 32

typedef _Float16 half8_t __attribute__((ext_vector_type(8)));
typedef float float4_t __attribute__((ext_vector_type(4)));

// ---------------------------------------------------------------------------
// Tiled SGEMM: C[M,N] = A[M,K] @ B[K,N] (+ bias[N] if bias != nullptr)
// 64x64 tile, BK=16, 256 threads, 4x4 micro-tile per thread.  (unchanged)
// ---------------------------------------------------------------------------
__global__ __launch_bounds__(256) void sgemm64(const float* __restrict__ A,
                                               const float* __restrict__ Bm,
                                               const float* __restrict__ bias,
                                               float* __restrict__ C,
                                               int M, int N, int K) {
    constexpr int BM = 64, BN = 64, BK = 16;
    __shared__ float As[BK][BM + 1];
    __shared__ float Bs[BK][BN];
    const int t  = threadIdx.x;
    const int tx = t & 15, ty = t >> 4;
    const int m0 = blockIdx.y * BM, n0 = blockIdx.x * BN;
    float c[4][4] = {};
    for (int k0 = 0; k0 < K; k0 += BK) {
        #pragma unroll
        for (int i = 0; i < 4; ++i) {
            int idx = t + i * 256;
            int k = idx & 15, m = idx >> 4;
            As[k][m] = A[(size_t)(m0 + m) * K + (k0 + k)];
        }
        #pragma unroll
        for (int i = 0; i < 4; ++i) {
            int idx = t + i * 256;
            int nn = idx & 63, k = idx >> 6;
            Bs[k][nn] = Bm[(size_t)(k0 + k) * N + (n0 + nn)];
        }
        __syncthreads();
        #pragma unroll
        for (int kk = 0; kk < BK; ++kk) {
            float a[4], b[4];
            #pragma unroll
            for (int i = 0; i < 4; ++i) a[i] = As[kk][ty * 4 + i];
            #pragma unroll
            for (int j = 0; j < 4; ++j) b[j] = Bs[kk][tx * 4 + j];
            #pragma unroll
            for (int i = 0; i < 4; ++i)
                #pragma unroll
                for (int j = 0; j < 4; ++j)
                    c[i][j] += a[i] * b[j];
        }
        __syncthreads();
    }
    #pragma unroll
    for (int i = 0; i < 4; ++i) {
        int m = m0 + ty * 4 + i;
        float4 v;
        v.x = c[i][0]; v.y = c[i][1]; v.z = c[i][2]; v.w = c[i][3];
        if (bias != nullptr) {
            const float4 bb = *reinterpret_cast<const float4*>(&bias[n0 + tx * 4]);
            v.x += bb.x; v.y += bb.y; v.z += bb.z; v.w += bb.w;
        }
        *reinterpret_cast<float4*>(&C[(size_t)m * N + n0 + tx * 4]) = v;
    }
}

// ---------------------------------------------------------------------------
// MFMA flash attention (unnormalized exp, matches KeOps reference):
// block = 4 waves = one (b, h, 64-query tile). Wave w owns q rows [w*16, w*16+16).
// Per 64-key tile: stage K (row-major fp16) and V (transposed fp16) in LDS;
// S = QK^T via 4 mfma_f32_16x16x32_f16 (K-dim = hd = 32 in one shot);
// e = expf(S); E -> fp16 -> LDS (per-wave private rows, A-fragment layout);
// numer += E@V via 4 mfma; denom accumulated in VALU from S fragments.
//
// Fragment layouts (m89/m120-verified, 16x16x32):
//   A: lane = quad*16+l16 holds A[m=l16][k=quad*8+j], j=0..7
//   B: lane holds B[k=quad*8+j][n=l16]
//   D: lane holds D[row=quad*4+r][col=l16], r=0..3
// ---------------------------------------------------------------------------
__global__ __launch_bounds__(256) void attn_mfma(const float* __restrict__ qkv,
                                                 float* __restrict__ outp, int n) {
    constexpr int LDK = 48;   // halves/row: 32 data + 16 pad (96B, 16B-multiple)
    constexpr int LDV = 72;   // halves/row: 64 data + 8 pad (144B)
    constexpr int LDE = 72;
    __shared__ alignas(16) _Float16 ks[64 * LDK];       // K-tile [key][hd]
    __shared__ alignas(16) _Float16 vsT[HDIM * LDV];    // V-tile transposed [hd][key]
    __shared__ alignas(16) _Float16 es[64 * LDE];       // E-tile [q][key], per-wave rows

    const int nqt = n / 64;
    const int bid = blockIdx.x;
    const int qt = bid % nqt;
    const int h  = (bid / nqt) % NHEADS;
    const int b  = bid / (nqt * NHEADS);
    const int t  = threadIdx.x;
    const int lane = t & 63;
    const int wave = t >> 6;
    const int l16  = lane & 15;
    const int quad = lane >> 4;
    const float scale = 0.17677669529663687f;  // 32^-0.5
    const float* base = qkv + (size_t)b * n * (3 * DIM);
    const int q0 = qt * 64 + wave * 16;

    // Q A-fragment: Q[q0+l16][quad*8+j] * scale, fp16, lives in regs all pass.
    half8_t qf;
    {
        const float* qp = base + (size_t)(q0 + l16) * (3 * DIM) + h * HDIM + quad * 8;
        float tmp[8];
        *reinterpret_cast<float4*>(tmp)     = *reinterpret_cast<const float4*>(qp);
        *reinterpret_cast<float4*>(tmp + 4) = *reinterpret_cast<const float4*>(qp + 4);
        #pragma unroll
        for (int j = 0; j < 8; ++j) qf[j] = (_Float16)(tmp[j] * scale);
    }

    float4_t numer0 = {0.f, 0.f, 0.f, 0.f};
    float4_t numer1 = {0.f, 0.f, 0.f, 0.f};
    float dsum[4] = {0.f, 0.f, 0.f, 0.f};

    // staging indices: thread covers K[kk][d0..d0+7] and V[kk][d0..d0+7]
    const int kk = t >> 2;
    const int d0 = (t & 3) * 8;

    for (int k0 = 0; k0 < n; k0 += 64) {
        // ---- stage K (row-major) + V (transposed) as fp16 ----
        {
            const float* kp = base + (size_t)(k0 + kk) * (3 * DIM) + DIM + h * HDIM + d0;
            float kt[8], vt[8];
            *reinterpret_cast<float4*>(kt)     = *reinterpret_cast<const float4*>(kp);
            *reinterpret_cast<float4*>(kt + 4) = *reinterpret_cast<const float4*>(kp + 4);
            *reinterpret_cast<float4*>(vt)     = *reinterpret_cast<const float4*>(kp + DIM);
            *reinterpret_cast<float4*>(vt + 4) = *reinterpret_cast<const float4*>(kp + DIM + 4);
            half8_t kh;
            #pragma unroll
            for (int j = 0; j < 8; ++j) kh[j] = (_Float16)kt[j];
            *reinterpret_cast<half8_t*>(&ks[kk * LDK + d0]) = kh;
            #pragma unroll
            for (int j = 0; j < 8; ++j) vsT[(d0 + j) * LDV + kk] = (_Float16)vt[j];
        }
        __syncthreads();

        // ---- S = QK^T : 4 MFMAs (one per 16-key block) ----
        float4_t sf[4];
        #pragma unroll
        for (int kb = 0; kb < 4; ++kb) {
            half8_t kf = *reinterpret_cast<const half8_t*>(
                &ks[(kb * 16 + l16) * LDK + quad * 8]);
            float4_t z = {0.f, 0.f, 0.f, 0.f};
            sf[kb] = __builtin_amdgcn_mfma_f32_16x16x32_f16(qf, kf, z, 0, 0, 0);
        }

        // ---- e = exp(s); denom accumulate; E -> LDS (fp16, A-layout rows) ----
        #pragma unroll
        for (int kb = 0; kb < 4; ++kb)
            #pragma unroll
            for (int r = 0; r < 4; ++r) {
                float e = __expf(sf[kb][r]);
                dsum[r] += e;
                es[(wave * 16 + quad * 4 + r) * LDE + kb * 16 + l16] = (_Float16)e;
            }
        // (es rows are per-wave private: no barrier needed, compiler inserts
        //  the lgkmcnt wait for the write->read dependency within the wave)

        // ---- numer += E @ V : 4 MFMAs ----
        #pragma unroll
        for (int s = 0; s < 2; ++s) {
            half8_t ef = *reinterpret_cast<const half8_t*>(
                &es[(wave * 16 + l16) * LDE + s * 32 + quad * 8]);
            half8_t vf0 = *reinterpret_cast<const half8_t*>(
                &vsT[l16 * LDV + s * 32 + quad * 8]);
            half8_t vf1 = *reinterpret_cast<const half8_t*>(
                &vsT[(16 + l16) * LDV + s * 32 + quad * 8]);
            numer0 = __builtin_amdgcn_mfma_f32_16x16x32_f16(ef, vf0, numer0, 0, 0, 0);
            numer1 = __builtin_amdgcn_mfma_f32_16x16x32_f16(ef, vf1, numer1, 0, 0, 0);
        }
        __syncthreads();   // protect ks/vsT before next stage
    }

    // ---- denom: reduce over the 16 lanes of each quad (cols of the row) ----
    #pragma unroll
    for (int off = 1; off < 16; off <<= 1)
        #pragma unroll
        for (int r = 0; r < 4; ++r)
            dsum[r] += __shfl_xor(dsum[r], off, 16);

    // ---- write out[q][h*32 + c] = numer / (denom + eps) ----
    float* ob = outp + ((size_t)b * n + q0) * DIM + h * HDIM;
    #pragma unroll
    for (int r = 0; r < 4; ++r) {
        int row = quad * 4 + r;
        float rcp = 1.0f / (dsum[r] + 1e-6f);
        ob[(size_t)row * DIM + l16]      = numer0[r] * rcp;
        ob[(size_t)row * DIM + 16 + l16] = numer1[r] * rcp;
    }
}

extern "C" void kernel_launch(void* const* d_in, const int* in_sizes, int n_in,
                              void* d_out, int out_size, void* d_ws, size_t ws_size,
                              hipStream_t stream) {
    const float* x    = (const float*)d_in[0];
    const float* Wqkv = (const float*)d_in[1];
    const float* Wout = (const float*)d_in[2];
    const float* bout = (const float*)d_in[3];
    float* out = (float*)d_out;
    const int B = 4, N = 2048;
    const int M = B * N;                       // 8192
    float* qkv  = (float*)d_ws;                // [8192, 768]
    float* attn = qkv + (size_t)M * 3 * DIM;   // [8192, 256]

    // qkv = x @ Wqkv
    dim3 g1(3 * DIM / 64, M / 64);
    hipLaunchKernelGGL(sgemm64, g1, dim3(256), 0, stream, x, Wqkv, nullptr, qkv,
                       M, 3 * DIM, DIM);
    // attention (MFMA)
    hipLaunchKernelGGL(attn_mfma, dim3(B * NHEADS * (N / 64)), dim3(256), 0, stream,
                       qkv, attn, N);
    // out = attn @ Wout + bout
    dim3 g2(DIM / 64, M / 64);
    hipLaunchKernelGGL(sgemm64, g2, dim3(256), 0, stream, attn, Wout, bout, out,
                       M, DIM, DIM);
}

// Round 3
// 141.686 us; speedup vs baseline: 3.7689x; 1.3943x over previous
//
#include <hip/hip_runtime.h>

#define DIM 256
#define NHEADS 8
#define HDIM 32

typedef _Float16 half8_t __attribute__((ext_vector_type(8)));
typedef float float4_t __attribute__((ext_vector_type(4)));

__device__ __forceinline__ void gload_lds16(const void* g, void* l) {
    __builtin_amdgcn_global_load_lds((const __attribute__((address_space(1))) void*)g,
                                     (__attribute__((address_space(3))) void*)l,
                                     16, 0, 0);
}

// ---------------------------------------------------------------------------
// prep: (a) x fp32 -> fp16 flat; (b) Wqkv [256,768] -> WqT [768,256] fp16;
//       (c) Wout [256,256] -> WoT [256,256] fp16 (transposed for B-frags).
// ---------------------------------------------------------------------------
__global__ __launch_bounds__(256) void prep(const float* __restrict__ x,
                                            const float* __restrict__ Wqkv,
                                            const float* __restrict__ Wout,
                                            _Float16* __restrict__ xh,
                                            _Float16* __restrict__ WqT,
                                            _Float16* __restrict__ WoT) {
    __shared__ float ts[32][33];
    const int bid = blockIdx.x, t = threadIdx.x;
    if (bid < 1024) {
        size_t idx = (size_t)bid * 2048 + (size_t)t * 8;
        float tmp[8];
        *reinterpret_cast<float4*>(tmp)     = *reinterpret_cast<const float4*>(x + idx);
        *reinterpret_cast<float4*>(tmp + 4) = *reinterpret_cast<const float4*>(x + idx + 4);
        half8_t h;
        #pragma unroll
        for (int j = 0; j < 8; ++j) h[j] = (_Float16)tmp[j];
        *reinterpret_cast<half8_t*>(xh + idx) = h;
    } else {
        const float* src; _Float16* dst; int K, N, kb, nb;
        if (bid < 1024 + 192) { int b2 = bid - 1024; src = Wqkv; dst = WqT; K = 256; N = 768; nb = b2 % 24; kb = b2 / 24; }
        else                  { int b3 = bid - 1216; src = Wout; dst = WoT; K = 256; N = 256; nb = b3 % 8;  kb = b3 / 8; }
        const int tx = t & 31, ty = t >> 5;
        #pragma unroll
        for (int i = 0; i < 4; ++i) {
            int k = kb * 32 + ty + i * 8;
            ts[ty + i * 8][tx] = src[(size_t)k * N + nb * 32 + tx];
        }
        __syncthreads();
        #pragma unroll
        for (int i = 0; i < 4; ++i) {
            int nl = ty + i * 8;
            dst[(size_t)(nb * 32 + nl) * K + kb * 32 + tx] = (_Float16)ts[tx][nl];
        }
    }
}

// ---------------------------------------------------------------------------
// fp16 MFMA GEMM: C[M,N] = A[M,K] @ BT[N,K]^T (+bias). 128x128 tile, BK=32,
// 4 waves (each 64x64), global_load_lds 16B staging, fp32 accumulate.
// ---------------------------------------------------------------------------
template <bool OUT_HALF>
__global__ __launch_bounds__(256) void gemm_h(const _Float16* __restrict__ A,
                                              const _Float16* __restrict__ BT,
                                              const float* __restrict__ bias,
                                              void* __restrict__ Cv,
                                              int M, int N, int K) {
    __shared__ alignas(16) _Float16 As[128 * 32];
    __shared__ alignas(16) _Float16 Bs[128 * 32];
    const int t = threadIdx.x, lane = t & 63, wave = t >> 6;
    const int l16 = lane & 15, quad = lane >> 4;
    const int m0 = blockIdx.y * 128, n0 = blockIdx.x * 128;
    const int wr = (wave >> 1) * 64, wc = (wave & 1) * 64;
    float4_t acc[4][4];
    #pragma unroll
    for (int i = 0; i < 4; ++i)
        #pragma unroll
        for (int j = 0; j < 4; ++j) acc[i][j] = (float4_t){0.f, 0.f, 0.f, 0.f};

    const int srow = lane >> 2;        // 0..15 within 16-row chunk
    const int scol = (lane & 3) * 8;   // halves

    for (int k0 = 0; k0 < K; k0 += 32) {
        #pragma unroll
        for (int i = 0; i < 2; ++i) {
            int chunk = i * 4 + wave;          // 0..7, each = 16 rows
            int r = chunk * 16 + srow;
            gload_lds16(A  + (size_t)(m0 + r) * K + k0 + scol, As + chunk * 512);
            gload_lds16(BT + (size_t)(n0 + r) * K + k0 + scol, Bs + chunk * 512);
        }
        __syncthreads();
        half8_t af[4], bf[4];
        #pragma unroll
        for (int i = 0; i < 4; ++i)
            af[i] = *reinterpret_cast<const half8_t*>(As + (wr + i * 16 + l16) * 32 + quad * 8);
        #pragma unroll
        for (int j = 0; j < 4; ++j)
            bf[j] = *reinterpret_cast<const half8_t*>(Bs + (wc + j * 16 + l16) * 32 + quad * 8);
        #pragma unroll
        for (int i = 0; i < 4; ++i)
            #pragma unroll
            for (int j = 0; j < 4; ++j)
                acc[i][j] = __builtin_amdgcn_mfma_f32_16x16x32_f16(af[i], bf[j], acc[i][j], 0, 0, 0);
        __syncthreads();
    }

    float bv[4] = {0.f, 0.f, 0.f, 0.f};
    if (bias != nullptr) {
        #pragma unroll
        for (int j = 0; j < 4; ++j) bv[j] = bias[n0 + wc + j * 16 + l16];
    }
    #pragma unroll
    for (int i = 0; i < 4; ++i)
        #pragma unroll
        for (int r = 0; r < 4; ++r) {
            int row = m0 + wr + i * 16 + quad * 4 + r;
            #pragma unroll
            for (int j = 0; j < 4; ++j) {
                int col = n0 + wc + j * 16 + l16;
                float v = acc[i][j][r] + bv[j];
                if (OUT_HALF) ((_Float16*)Cv)[(size_t)row * N + col] = (_Float16)v;
                else          ((float*)Cv)[(size_t)row * N + col] = v;
            }
        }
}

// ---------------------------------------------------------------------------
// MFMA flash attention, fp16 I/O. Block = 4 waves = (b, h, 64-q tile).
// Q: direct global A-frag (scale folded into exp). K: global_load_lds, plain
// [key][32] layout. V: transposed into XOR-swizzled [hd][key] (16B blocks,
// phys_blk = keyblk ^ ((hd + 2*(hd>>3))&7) -> write banks 2-way = free).
// E: [q][key] swizzled phys_blk = colblk ^ (((q>>2)&3)*2), per-wave rows.
// exp(s*scale) unnormalized, denom in VALU + shfl, out fp16.
// ---------------------------------------------------------------------------
__global__ __launch_bounds__(256) void attn_mfma(const _Float16* __restrict__ qkv,
                                                 _Float16* __restrict__ outp, int n) {
    __shared__ alignas(16) _Float16 ks[64 * 32];
    __shared__ alignas(16) _Float16 vsT[32 * 64];
    __shared__ alignas(16) _Float16 es[64 * 64];
    const int nqt = n / 64;
    const int bid = blockIdx.x;
    const int qt = bid % nqt;
    const int h  = (bid / nqt) % NHEADS;
    const int b  = bid / (nqt * NHEADS);
    const int t  = threadIdx.x, lane = t & 63, wave = t >> 6;
    const int l16 = lane & 15, quad = lane >> 4;
    const float scale = 0.17677669529663687f;  // 32^-0.5
    const _Float16* base = qkv + (size_t)b * n * (3 * DIM);
    const int q0 = qt * 64 + wave * 16;

    // Q A-fragment straight from global (fp16), unscaled.
    half8_t qf = *reinterpret_cast<const half8_t*>(
        base + (size_t)(q0 + l16) * (3 * DIM) + h * HDIM + quad * 8);

    float4_t numer0 = {0.f, 0.f, 0.f, 0.f};
    float4_t numer1 = {0.f, 0.f, 0.f, 0.f};
    float dsum[4] = {0.f, 0.f, 0.f, 0.f};

    const int kk = t >> 2;        // 0..63 key
    const int d0 = (t & 3) * 8;   // hd start

    for (int k0 = 0; k0 < n; k0 += 64) {
        // K: DMA 16 keys per wave into plain [key][32] layout
        gload_lds16(base + (size_t)(k0 + wave * 16 + (lane >> 2)) * (3 * DIM)
                        + DIM + h * HDIM + (lane & 3) * 8,
                    ks + wave * 512);
        // V: half8 load, transpose-scatter into swizzled vsT
        half8_t vt = *reinterpret_cast<const half8_t*>(
            base + (size_t)(k0 + kk) * (3 * DIM) + 2 * DIM + h * HDIM + d0);
        #pragma unroll
        for (int j = 0; j < 8; ++j) {
            int hd = d0 + j;
            int swz = (hd + 2 * (hd >> 3)) & 7;
            int phys8 = (kk >> 3) ^ swz;
            vsT[hd * 64 + phys8 * 8 + (kk & 7)] = vt[j];
        }
        __syncthreads();

        // S = QK^T : 4 MFMAs
        float4_t sf[4];
        #pragma unroll
        for (int kb = 0; kb < 4; ++kb) {
            half8_t kf = *reinterpret_cast<const half8_t*>(ks + (kb * 16 + l16) * 32 + quad * 8);
            float4_t z = {0.f, 0.f, 0.f, 0.f};
            sf[kb] = __builtin_amdgcn_mfma_f32_16x16x32_f16(qf, kf, z, 0, 0, 0);
        }

        // e = exp(s*scale); denom; E -> swizzled LDS (per-wave private rows)
        #pragma unroll
        for (int kb = 0; kb < 4; ++kb)
            #pragma unroll
            for (int r = 0; r < 4; ++r) {
                float e = __expf(sf[kb][r] * scale);
                dsum[r] += e;
                int qrow = wave * 16 + quad * 4 + r;
                int col  = kb * 16 + l16;
                int swz  = ((qrow >> 2) & 3) * 2;
                int phys8 = (col >> 3) ^ swz;
                es[qrow * 64 + phys8 * 8 + (col & 7)] = (_Float16)e;
            }

        // numer += E @ V : 4 MFMAs
        #pragma unroll
        for (int s = 0; s < 2; ++s) {
            int qrow = wave * 16 + l16;
            int swzq = ((qrow >> 2) & 3) * 2;
            half8_t ef = *reinterpret_cast<const half8_t*>(
                es + qrow * 64 + (((s * 4 + quad) ^ swzq) * 8));
            int hd0 = l16, hd1 = 16 + l16;
            int swv0 = (hd0 + 2 * (hd0 >> 3)) & 7;
            int swv1 = (hd1 + 2 * (hd1 >> 3)) & 7;
            half8_t vf0 = *reinterpret_cast<const half8_t*>(
                vsT + hd0 * 64 + (((s * 4 + quad) ^ swv0) * 8));
            half8_t vf1 = *reinterpret_cast<const half8_t*>(
                vsT + hd1 * 64 + (((s * 4 + quad) ^ swv1) * 8));
            numer0 = __builtin_amdgcn_mfma_f32_16x16x32_f16(ef, vf0, numer0, 0, 0, 0);
            numer1 = __builtin_amdgcn_mfma_f32_16x16x32_f16(ef, vf1, numer1, 0, 0, 0);
        }
        __syncthreads();
    }

    // denom: reduce across the 16 lanes of each quad
    #pragma unroll
    for (int off = 1; off < 16; off <<= 1)
        #pragma unroll
        for (int r = 0; r < 4; ++r) dsum[r] += __shfl_xor(dsum[r], off, 16);

    _Float16* ob = outp + ((size_t)b * n + q0) * DIM + h * HDIM;
    #pragma unroll
    for (int r = 0; r < 4; ++r) {
        int row = quad * 4 + r;
        float rcp = 1.0f / (dsum[r] + 1e-6f);
        ob[(size_t)row * DIM + l16]      = (_Float16)(numer0[r] * rcp);
        ob[(size_t)row * DIM + 16 + l16] = (_Float16)(numer1[r] * rcp);
    }
}

extern "C" void kernel_launch(void* const* d_in, const int* in_sizes, int n_in,
                              void* d_out, int out_size, void* d_ws, size_t ws_size,
                              hipStream_t stream) {
    const float* x    = (const float*)d_in[0];
    const float* Wqkv = (const float*)d_in[1];
    const float* Wout = (const float*)d_in[2];
    const float* bout = (const float*)d_in[3];
    float* out = (float*)d_out;
    const int B = 4, N = 2048;
    const int M = B * N;  // 8192

    _Float16* xh    = (_Float16*)d_ws;                 // [8192,256]
    _Float16* WqT   = xh + (size_t)M * DIM;            // [768,256]
    _Float16* WoT   = WqT + 768 * 256;                 // [256,256]
    _Float16* qkvh  = WoT + 256 * 256;                 // [8192,768]
    _Float16* attnh = qkvh + (size_t)M * 3 * DIM;      // [8192,256]

    hipLaunchKernelGGL(prep, dim3(1280), dim3(256), 0, stream, x, Wqkv, Wout, xh, WqT, WoT);
    hipLaunchKernelGGL((gemm_h<true>), dim3(6, 64), dim3(256), 0, stream,
                       xh, WqT, (const float*)nullptr, (void*)qkvh, M, 3 * DIM, DIM);
    hipLaunchKernelGGL(attn_mfma, dim3(B * NHEADS * (N / 64)), dim3(256), 0, stream,
                       qkvh, attnh, N);
    hipLaunchKernelGGL((gemm_h<false>), dim3(2, 64), dim3(256), 0, stream,
                       attnh, WoT, bout, (void*)out, M, DIM, DIM);
}